// Round 13
// baseline (143.468 us; speedup 1.0000x reference)
//
#include <hip/hip_runtime.h>
#include <hip/hip_bf16.h>

#define D_SRC 256
#define D_REL 128

typedef __bf16 bf16x8 __attribute__((ext_vector_type(8)));
typedef float f32x4 __attribute__((ext_vector_type(4)));
typedef float f32x2 __attribute__((ext_vector_type(2)));

typedef const __attribute__((address_space(1))) void GASV;
typedef __attribute__((address_space(3))) void LASV;

// ---------------- prep: W fragments + zero deg_i ----------------
// Wt[(ks*8+n)*64 + lane] = bf16x8 { W[ks*32 + (lane>>4)*8 + j][n*16 + (lane&15)] , j=0..7 }
// Used as A-operand of mfma(Wt, x^T): A[m][k] = W[k][m] = W^T.
__global__ __launch_bounds__(64) void prep_w_kernel(const float* __restrict__ W,
                                                    bf16x8* __restrict__ Wt,
                                                    int* __restrict__ deg_i, int ndeg) {
    int c = blockIdx.x;            // 0..63 = ks*8 + n
    int ks = c >> 3, n = c & 7;
    int lane = threadIdx.x;
    int col = n * 16 + (lane & 15);
    int k0 = ks * 32 + (lane >> 4) * 8;
    bf16x8 v;
#pragma unroll
    for (int j = 0; j < 8; ++j) v[j] = (__bf16)W[(size_t)(k0 + j) * D_REL + col];
    Wt[c * 64 + lane] = v;
    // grid-stride zero of deg_i (4096 threads)
    for (int i = blockIdx.x * 64 + lane; i < ndeg; i += 64 * 64) deg_i[i] = 0;
}

// ---------------- projection GEMM: p_bf = bf16(x @ W) — bf16 store ONLY ----------------
// 4 waves / 32 rows per block. x staged via global_load_lds (XOR-swizzled both sides);
// W^T frags register-pinned.
__global__ __launch_bounds__(256, 4) void proj_gemm_kernel(
    const float* __restrict__ x, const f32x4* __restrict__ Wt,
    unsigned short* __restrict__ out_bf, int M) {
    __shared__ float xlds[32 * 256];   // 32 KB: [row][64 slots of 16B], slot-swizzled
    int tid = threadIdx.x;
    int wid = tid >> 6, lane = tid & 63;
    int r = lane & 15, kq = lane >> 4;
    int row0 = blockIdx.x * 32;

    // stage x rows [row0, row0+32): wave w stages rows w*8..w*8+7.
    // LDS phys slot = lane; source slot = lane ^ (row&7).
#pragma unroll
    for (int j = 0; j < 8; ++j) {
        int rl = wid * 8 + j;
        int grow = min(row0 + rl, M - 1);
        const float* src = x + (size_t)grow * D_SRC + ((lane ^ j) << 2);
        __builtin_amdgcn_global_load_lds((GASV*)src, (LASV*)&xlds[rl * 256], 16, 0, 0);
    }

    // W^T fragments, register-resident (asm pin prevents rematerialization)
    f32x4 wfv[2][8];
#pragma unroll
    for (int s = 0; s < 2; ++s)
#pragma unroll
        for (int ks = 0; ks < 8; ++ks)
            wfv[s][ks] = Wt[(ks * 8 + wid * 2 + s) * 64 + lane];
#pragma unroll
    for (int s = 0; s < 2; ++s)
#pragma unroll
        for (int ks = 0; ks < 8; ++ks)
            asm volatile("" : "+v"(wfv[s][ks]));

    __syncthreads();   // drains vmcnt: staging + wf loads complete

    f32x4 acc[2][2];
#pragma unroll
    for (int t = 0; t < 2; ++t)
#pragma unroll
        for (int s = 0; s < 2; ++s) acc[t][s] = (f32x4)(0.f);

    const f32x4* xl = (const f32x4*)xlds;
    int r8 = r & 7;
#pragma unroll
    for (int ks = 0; ks < 8; ++ks) {
        int q0 = ks * 8 + kq * 2;
#pragma unroll
        for (int t = 0; t < 2; ++t) {
            int rl = t * 16 + r;
            f32x4 a0 = xl[rl * 64 + (q0 ^ r8)];
            f32x4 a1 = xl[rl * 64 + ((q0 + 1) ^ r8)];
            bf16x8 xf;
            xf[0] = (__bf16)a0[0]; xf[1] = (__bf16)a0[1];
            xf[2] = (__bf16)a0[2]; xf[3] = (__bf16)a0[3];
            xf[4] = (__bf16)a1[0]; xf[5] = (__bf16)a1[1];
            xf[6] = (__bf16)a1[2]; xf[7] = (__bf16)a1[3];
            acc[t][0] = __builtin_amdgcn_mfma_f32_16x16x32_bf16(
                __builtin_bit_cast(bf16x8, wfv[0][ks]), xf, acc[t][0], 0, 0, 0);
            acc[t][1] = __builtin_amdgcn_mfma_f32_16x16x32_bf16(
                __builtin_bit_cast(bf16x8, wfv[1][ks]), xf, acc[t][1], 0, 0, 0);
        }
    }

    // store bf16 only: lane holds p[row0+t*16+r][wid*32 + s*16 + kq*4 + reg]
    int col0 = wid * 32;
#pragma unroll
    for (int t = 0; t < 2; ++t) {
        int prow = row0 + t * 16 + r;
        if (prow < M) {
            size_t o0 = (size_t)prow * D_REL + col0 + kq * 4;
            ushort4 b0, b1;
            b0.x = __bfloat16_as_ushort(__float2bfloat16(acc[t][0][0]));
            b0.y = __bfloat16_as_ushort(__float2bfloat16(acc[t][0][1]));
            b0.z = __bfloat16_as_ushort(__float2bfloat16(acc[t][0][2]));
            b0.w = __bfloat16_as_ushort(__float2bfloat16(acc[t][0][3]));
            b1.x = __bfloat16_as_ushort(__float2bfloat16(acc[t][1][0]));
            b1.y = __bfloat16_as_ushort(__float2bfloat16(acc[t][1][1]));
            b1.z = __bfloat16_as_ushort(__float2bfloat16(acc[t][1][2]));
            b1.w = __bfloat16_as_ushort(__float2bfloat16(acc[t][1][3]));
            *(ushort4*)(out_bf + o0) = b0;
            *(ushort4*)(out_bf + o0 + 16) = b1;
        }
    }
}

// ---------------- fused: f32 expansion (stream, NT stores) + edge degree count ----------------
// Blocks [0, ncvt): convert p_bf -> out_psrc f32 (nontemporal).
// Blocks [ncvt, ncvt+ncb): grid-stride count: pos_arr[e] = atomicAdd(deg_i[dst], 1).
__global__ __launch_bounds__(256) void convert_count_kernel(
    const uint4* __restrict__ p_bf, float* __restrict__ out, int n8,
    const int* __restrict__ edge_dst, int* __restrict__ deg_i,
    int* __restrict__ pos_arr, int E, int ncvt, int ncb) {
    if (blockIdx.x >= ncvt) {
        int cb = blockIdx.x - ncvt;
        int stride = ncb * 256;
        for (int e = cb * 256 + threadIdx.x; e < E; e += stride)
            pos_arr[e] = atomicAdd(&deg_i[edge_dst[e]], 1);
        return;
    }
    int i = blockIdx.x * 256 + threadIdx.x;   // one uint4 = 8 bf16 = 8 floats
    if (i >= n8) return;
    uint4 v = p_bf[i];
    f32x4 lo, hi;
    lo[0] = __uint_as_float(v.x << 16);
    lo[1] = __uint_as_float(v.x & 0xffff0000u);
    lo[2] = __uint_as_float(v.y << 16);
    lo[3] = __uint_as_float(v.y & 0xffff0000u);
    hi[0] = __uint_as_float(v.z << 16);
    hi[1] = __uint_as_float(v.z & 0xffff0000u);
    hi[2] = __uint_as_float(v.w << 16);
    hi[3] = __uint_as_float(v.w & 0xffff0000u);
    f32x4* o = (f32x4*)(out + (size_t)i * 8);
    __builtin_nontemporal_store(lo, o);
    __builtin_nontemporal_store(hi, o + 1);
}

// ---------------- scan: per-block inclusive prefix + block sums ----------------
__global__ __launch_bounds__(1024) void scan_blocks(
    const int* __restrict__ deg_i, int* __restrict__ incl,
    int* __restrict__ bsums, int n) {
    int i = blockIdx.x * 1024 + threadIdx.x;
    int v = (i < n) ? deg_i[i] : 0;
    int lane = threadIdx.x & 63;
    int wid = threadIdx.x >> 6;
    int x = v;
#pragma unroll
    for (int off = 1; off < 64; off <<= 1) {
        int y = __shfl_up(x, off, 64);
        if (lane >= off) x += y;
    }
    __shared__ int wsum[16];
    if (lane == 63) wsum[wid] = x;
    __syncthreads();
    if (wid == 0 && lane < 16) {
        int s = wsum[lane];
#pragma unroll
        for (int off = 1; off < 16; off <<= 1) {
            int y = __shfl_up(s, off, 64);
            if (lane >= off) s += y;
        }
        wsum[lane] = s;
    }
    __syncthreads();
    int add = (wid > 0) ? wsum[wid - 1] : 0;
    x += add;
    if (i < n) incl[i] = x;
    if (threadIdx.x == 1023) bsums[blockIdx.x] = x;   // raw block sum
}

// ---------------- finalize: self-computed block offset + row_start + deg ----------------
__global__ __launch_bounds__(1024) void finalize_kernel(
    const int* __restrict__ deg_i, const int* __restrict__ incl,
    const int* __restrict__ bsums, int* __restrict__ row_start,
    float* __restrict__ deg_out, int n, int E) {
    __shared__ int soff;
    int bid = blockIdx.x;
    if (threadIdx.x < 64) {
        int lane = threadIdx.x;
        int s = 0;
        for (int i = lane; i < bid; i += 64) s += bsums[i];
#pragma unroll
        for (int m = 32; m >= 1; m >>= 1) s += __shfl_xor(s, m, 64);
        if (lane == 0) soff = s;
    }
    __syncthreads();
    int off = soff;
    int i = bid * 1024 + threadIdx.x;
    if (i < n) {
        row_start[i] = off + incl[i] - deg_i[i];
        deg_out[i] = (float)max(deg_i[i], 1);
    }
    if (i == 0) row_start[n] = E;
}

// ---------------- bucket fill (atomic-free) ----------------
__global__ void fill_kernel(const int* __restrict__ edge_src,
                            const int* __restrict__ edge_dst,
                            const int* __restrict__ row_start,
                            const int* __restrict__ pos_arr,
                            int* __restrict__ bucket, int E) {
    int e = blockIdx.x * 256 + threadIdx.x;
    if (e < E) {
        int d = edge_dst[e];
        bucket[row_start[d] + pos_arr[e]] = edge_src[e];
    }
}

// ---------------- gather: one wave per dst row, bf16 source, 8-deep pipeline ----------------
__global__ __launch_bounds__(256) void gather_kernel(
    const unsigned int* __restrict__ p_bf, const int* __restrict__ row_start,
    const int* __restrict__ bucket, const float* __restrict__ deg_out,
    float* __restrict__ dst, int n) {
    int row = blockIdx.x * 4 + (threadIdx.x >> 6);
    int lane = threadIdx.x & 63;
    if (row >= n) return;
    int beg = row_start[row], end = row_start[row + 1];
    float ax = 0.f, ay = 0.f;
    int idx = beg;
    for (; idx + 8 <= end; idx += 8) {
        int s[8];
        unsigned int v[8];
#pragma unroll
        for (int u = 0; u < 8; ++u) s[u] = bucket[idx + u];
#pragma unroll
        for (int u = 0; u < 8; ++u) v[u] = p_bf[(size_t)s[u] * 64 + lane];
#pragma unroll
        for (int u = 0; u < 8; ++u) {
            ax += __uint_as_float(v[u] << 16);
            ay += __uint_as_float(v[u] & 0xffff0000u);
        }
    }
    for (; idx + 4 <= end; idx += 4) {
        int s0 = bucket[idx + 0], s1 = bucket[idx + 1];
        int s2 = bucket[idx + 2], s3 = bucket[idx + 3];
        unsigned int v0 = p_bf[(size_t)s0 * 64 + lane];
        unsigned int v1 = p_bf[(size_t)s1 * 64 + lane];
        unsigned int v2 = p_bf[(size_t)s2 * 64 + lane];
        unsigned int v3 = p_bf[(size_t)s3 * 64 + lane];
        ax += __uint_as_float(v0 << 16) + __uint_as_float(v1 << 16)
            + __uint_as_float(v2 << 16) + __uint_as_float(v3 << 16);
        ay += __uint_as_float(v0 & 0xffff0000u) + __uint_as_float(v1 & 0xffff0000u)
            + __uint_as_float(v2 & 0xffff0000u) + __uint_as_float(v3 & 0xffff0000u);
    }
    for (; idx < end; ++idx) {
        int s = bucket[idx];
        unsigned int v = p_bf[(size_t)s * 64 + lane];
        ax += __uint_as_float(v << 16);
        ay += __uint_as_float(v & 0xffff0000u);
    }
    float dinv = 1.0f / deg_out[row];
    f32x2 o;
    o[0] = ax * dinv;
    o[1] = ay * dinv;
    f32x2* dp = (f32x2*)dst + (size_t)row * 64 + lane;
    __builtin_nontemporal_store(o, dp);
}

extern "C" void kernel_launch(void* const* d_in, const int* in_sizes, int n_in,
                              void* d_out, int out_size, void* d_ws, size_t ws_size,
                              hipStream_t stream) {
    const float* x_src = (const float*)d_in[0];
    const float* W_src = (const float*)d_in[2];
    const int* edge_src = (const int*)d_in[4];
    const int* edge_dst = (const int*)d_in[5];

    const int N_SRC = in_sizes[0] / D_SRC;
    const int N_DST = in_sizes[1] / D_SRC;
    const int E = in_sizes[4];

    float* out_dst = (float*)d_out;                          // [N_DST, 128]
    float* out_psrc = out_dst + (size_t)N_DST * D_REL;       // [N_SRC, 128]
    float* out_deg = out_psrc + (size_t)N_SRC * D_REL;       // [N_DST]

    int* deg_i = (int*)d_ws;               // N_DST
    int* incl = deg_i + N_DST;             // N_DST
    int* row_start = incl + N_DST;         // N_DST+1
    int* bsums = row_start + N_DST + 1;    // 128
    int* pos_arr = bsums + 128;            // E
    int* bucket = pos_arr + E;             // E
    size_t int_bytes = (size_t)(3 * N_DST + 1 + 128 + 2 * (size_t)E) * sizeof(int);
    size_t wt_off = (int_bytes + 255) & ~(size_t)255;
    bf16x8* Wt = (bf16x8*)((char*)d_ws + wt_off);            // 64 KB
    size_t pbf_off = wt_off + 65536;
    unsigned short* p_bf = (unsigned short*)((char*)d_ws + pbf_off);  // N_SRC*128 bf16

    // 1. W fragments + zero deg_i (no hipMemsetAsync: fillBuffer costs ~58us/replay)
    prep_w_kernel<<<64, 64, 0, stream>>>(W_src, Wt, deg_i, N_DST);
    // 2. projection GEMM -> p_bf (bf16 only)
    proj_gemm_kernel<<<(N_SRC + 31) / 32, 256, 0, stream>>>(
        x_src, (const f32x4*)Wt, p_bf, N_SRC);
    // 3. fused: expand p_bf -> f32 out_psrc (NT) + edge degree count
    {
        int n8 = N_SRC * D_REL / 8;
        int ncvt = (n8 + 255) / 256;
        int ncb = 768;
        convert_count_kernel<<<ncvt + ncb, 256, 0, stream>>>(
            (const uint4*)p_bf, out_psrc, n8, edge_dst, deg_i, pos_arr, E, ncvt, ncb);
    }
    // 4. scan + finalize
    int nb = (N_DST + 1023) / 1024;
    scan_blocks<<<nb, 1024, 0, stream>>>(deg_i, incl, bsums, N_DST);
    finalize_kernel<<<nb, 1024, 0, stream>>>(deg_i, incl, bsums, row_start, out_deg, N_DST, E);
    // 5. bucket fill (atomic-free)
    fill_kernel<<<(E + 255) / 256, 256, 0, stream>>>(edge_src, edge_dst, row_start, pos_arr, bucket, E);
    // 6. gather + normalize (bf16 source)
    gather_kernel<<<(N_DST + 3) / 4, 256, 0, stream>>>(
        (const unsigned int*)p_bf, row_start, bucket, out_deg, out_dst, N_DST);
}

// Round 14
// 129.855 us; speedup vs baseline: 1.1048x; 1.1048x over previous
//
#include <hip/hip_runtime.h>
#include <hip/hip_bf16.h>

#define D_SRC 256
#define D_REL 128

typedef __bf16 bf16x8 __attribute__((ext_vector_type(8)));
typedef float f32x4 __attribute__((ext_vector_type(4)));
typedef float f32x2 __attribute__((ext_vector_type(2)));

typedef const __attribute__((address_space(1))) void GASV;
typedef __attribute__((address_space(3))) void LASV;

// ---------------- prep: W fragments + zero deg_i ----------------
// Wt[(ks*8+n)*64 + lane] = bf16x8 { W[ks*32 + (lane>>4)*8 + j][n*16 + (lane&15)] , j=0..7 }
// Used as A-operand of mfma(Wt, x^T): A[m][k] = W[k][m] = W^T.
__global__ __launch_bounds__(64) void prep_w_kernel(const float* __restrict__ W,
                                                    bf16x8* __restrict__ Wt,
                                                    int* __restrict__ deg_i, int ndeg) {
    int c = blockIdx.x;            // 0..63 = ks*8 + n
    int ks = c >> 3, n = c & 7;
    int lane = threadIdx.x;
    int col = n * 16 + (lane & 15);
    int k0 = ks * 32 + (lane >> 4) * 8;
    bf16x8 v;
#pragma unroll
    for (int j = 0; j < 8; ++j) v[j] = (__bf16)W[(size_t)(k0 + j) * D_REL + col];
    Wt[c * 64 + lane] = v;
    // grid-stride zero of deg_i (4096 threads)
    for (int i = blockIdx.x * 64 + lane; i < ndeg; i += 64 * 64) deg_i[i] = 0;
}

// ---------------- fused: edge degree count (FIRST blocks) + projection GEMM ----------------
// Blocks [0, ncb): grid-stride count: pos_arr[e] = atomicAdd(deg_i[dst], 1) — launched
//   first so the atomic work overlaps proj instead of trailing it.
// Blocks [ncb, ncb+nproj): proj — 4 waves / 32 rows, x staged via global_load_lds
//   (XOR-swizzled both sides), W^T frags register-pinned; stores f32 (nontemporal,
//   never re-read) + bf16 (cached, gather reads it).
__global__ __launch_bounds__(256, 4) void proj_count_kernel(
    const float* __restrict__ x, const f32x4* __restrict__ Wt,
    float* __restrict__ out_f32, unsigned short* __restrict__ out_bf, int M,
    const int* __restrict__ edge_dst, int* __restrict__ deg_i,
    int* __restrict__ pos_arr, int E, int ncb) {
    __shared__ float xlds[32 * 256];   // 32 KB: [row][64 slots of 16B], slot-swizzled
    int tid = threadIdx.x;

    if (blockIdx.x < ncb) {
        // ---- count path (overlaps proj) ----
        int stride = ncb * 256;
        for (int e = blockIdx.x * 256 + tid; e < E; e += stride)
            pos_arr[e] = atomicAdd(&deg_i[edge_dst[e]], 1);
        return;
    }

    // ---- proj path ----
    int bid = blockIdx.x - ncb;
    int wid = tid >> 6, lane = tid & 63;
    int r = lane & 15, kq = lane >> 4;
    int row0 = bid * 32;

    // stage x rows [row0, row0+32): wave w stages rows w*8..w*8+7.
    // LDS phys slot = lane; source slot = lane ^ (row&7).
#pragma unroll
    for (int j = 0; j < 8; ++j) {
        int rl = wid * 8 + j;
        int grow = min(row0 + rl, M - 1);
        const float* src = x + (size_t)grow * D_SRC + ((lane ^ j) << 2);
        __builtin_amdgcn_global_load_lds((GASV*)src, (LASV*)&xlds[rl * 256], 16, 0, 0);
    }

    // W^T fragments, register-resident (asm pin prevents rematerialization)
    f32x4 wfv[2][8];
#pragma unroll
    for (int s = 0; s < 2; ++s)
#pragma unroll
        for (int ks = 0; ks < 8; ++ks)
            wfv[s][ks] = Wt[(ks * 8 + wid * 2 + s) * 64 + lane];
#pragma unroll
    for (int s = 0; s < 2; ++s)
#pragma unroll
        for (int ks = 0; ks < 8; ++ks)
            asm volatile("" : "+v"(wfv[s][ks]));

    __syncthreads();   // drains vmcnt: staging + wf loads complete

    f32x4 acc[2][2];
#pragma unroll
    for (int t = 0; t < 2; ++t)
#pragma unroll
        for (int s = 0; s < 2; ++s) acc[t][s] = (f32x4)(0.f);

    const f32x4* xl = (const f32x4*)xlds;
    int r8 = r & 7;
#pragma unroll
    for (int ks = 0; ks < 8; ++ks) {
        int q0 = ks * 8 + kq * 2;
#pragma unroll
        for (int t = 0; t < 2; ++t) {
            int rl = t * 16 + r;
            f32x4 a0 = xl[rl * 64 + (q0 ^ r8)];
            f32x4 a1 = xl[rl * 64 + ((q0 + 1) ^ r8)];
            bf16x8 xf;
            xf[0] = (__bf16)a0[0]; xf[1] = (__bf16)a0[1];
            xf[2] = (__bf16)a0[2]; xf[3] = (__bf16)a0[3];
            xf[4] = (__bf16)a1[0]; xf[5] = (__bf16)a1[1];
            xf[6] = (__bf16)a1[2]; xf[7] = (__bf16)a1[3];
            acc[t][0] = __builtin_amdgcn_mfma_f32_16x16x32_bf16(
                __builtin_bit_cast(bf16x8, wfv[0][ks]), xf, acc[t][0], 0, 0, 0);
            acc[t][1] = __builtin_amdgcn_mfma_f32_16x16x32_bf16(
                __builtin_bit_cast(bf16x8, wfv[1][ks]), xf, acc[t][1], 0, 0, 0);
        }
    }

    // store: lane holds p[row0+t*16+r][wid*32 + s*16 + kq*4 + reg]
    int col0 = wid * 32;
#pragma unroll
    for (int t = 0; t < 2; ++t) {
        int prow = row0 + t * 16 + r;
        if (prow < M) {
            size_t o0 = (size_t)prow * D_REL + col0 + kq * 4;
            __builtin_nontemporal_store(acc[t][0], (f32x4*)(out_f32 + o0));
            __builtin_nontemporal_store(acc[t][1], (f32x4*)(out_f32 + o0 + 16));
            ushort4 b0, b1;
            b0.x = __bfloat16_as_ushort(__float2bfloat16(acc[t][0][0]));
            b0.y = __bfloat16_as_ushort(__float2bfloat16(acc[t][0][1]));
            b0.z = __bfloat16_as_ushort(__float2bfloat16(acc[t][0][2]));
            b0.w = __bfloat16_as_ushort(__float2bfloat16(acc[t][0][3]));
            b1.x = __bfloat16_as_ushort(__float2bfloat16(acc[t][1][0]));
            b1.y = __bfloat16_as_ushort(__float2bfloat16(acc[t][1][1]));
            b1.z = __bfloat16_as_ushort(__float2bfloat16(acc[t][1][2]));
            b1.w = __bfloat16_as_ushort(__float2bfloat16(acc[t][1][3]));
            *(ushort4*)(out_bf + o0) = b0;
            *(ushort4*)(out_bf + o0 + 16) = b1;
        }
    }
}

// ---------------- scan: per-block inclusive prefix + block sums ----------------
__global__ __launch_bounds__(1024) void scan_blocks(
    const int* __restrict__ deg_i, int* __restrict__ incl,
    int* __restrict__ bsums, int n) {
    int i = blockIdx.x * 1024 + threadIdx.x;
    int v = (i < n) ? deg_i[i] : 0;
    int lane = threadIdx.x & 63;
    int wid = threadIdx.x >> 6;
    int x = v;
#pragma unroll
    for (int off = 1; off < 64; off <<= 1) {
        int y = __shfl_up(x, off, 64);
        if (lane >= off) x += y;
    }
    __shared__ int wsum[16];
    if (lane == 63) wsum[wid] = x;
    __syncthreads();
    if (wid == 0 && lane < 16) {
        int s = wsum[lane];
#pragma unroll
        for (int off = 1; off < 16; off <<= 1) {
            int y = __shfl_up(s, off, 64);
            if (lane >= off) s += y;
        }
        wsum[lane] = s;
    }
    __syncthreads();
    int add = (wid > 0) ? wsum[wid - 1] : 0;
    x += add;
    if (i < n) incl[i] = x;
    if (threadIdx.x == 1023) bsums[blockIdx.x] = x;   // raw block sum
}

// ---------------- finalize: self-computed block offset + row_start + deg ----------------
__global__ __launch_bounds__(1024) void finalize_kernel(
    const int* __restrict__ deg_i, const int* __restrict__ incl,
    const int* __restrict__ bsums, int* __restrict__ row_start,
    float* __restrict__ deg_out, int n, int E) {
    __shared__ int soff;
    int bid = blockIdx.x;
    if (threadIdx.x < 64) {
        int lane = threadIdx.x;
        int s = 0;
        for (int i = lane; i < bid; i += 64) s += bsums[i];
#pragma unroll
        for (int m = 32; m >= 1; m >>= 1) s += __shfl_xor(s, m, 64);
        if (lane == 0) soff = s;
    }
    __syncthreads();
    int off = soff;
    int i = bid * 1024 + threadIdx.x;
    if (i < n) {
        row_start[i] = off + incl[i] - deg_i[i];
        deg_out[i] = (float)max(deg_i[i], 1);
    }
    if (i == 0) row_start[n] = E;
}

// ---------------- bucket fill (atomic-free) ----------------
__global__ void fill_kernel(const int* __restrict__ edge_src,
                            const int* __restrict__ edge_dst,
                            const int* __restrict__ row_start,
                            const int* __restrict__ pos_arr,
                            int* __restrict__ bucket, int E) {
    int e = blockIdx.x * 256 + threadIdx.x;
    if (e < E) {
        int d = edge_dst[e];
        bucket[row_start[d] + pos_arr[e]] = edge_src[e];
    }
}

// ---------------- gather: one wave per dst row, bf16 source, 8-deep pipeline ----------------
__global__ __launch_bounds__(256) void gather_kernel(
    const unsigned int* __restrict__ p_bf, const int* __restrict__ row_start,
    const int* __restrict__ bucket, const float* __restrict__ deg_out,
    float* __restrict__ dst, int n) {
    int row = blockIdx.x * 4 + (threadIdx.x >> 6);
    int lane = threadIdx.x & 63;
    if (row >= n) return;
    int beg = row_start[row], end = row_start[row + 1];
    float ax = 0.f, ay = 0.f;
    int idx = beg;
    for (; idx + 8 <= end; idx += 8) {
        int s[8];
        unsigned int v[8];
#pragma unroll
        for (int u = 0; u < 8; ++u) s[u] = bucket[idx + u];
#pragma unroll
        for (int u = 0; u < 8; ++u) v[u] = p_bf[(size_t)s[u] * 64 + lane];
#pragma unroll
        for (int u = 0; u < 8; ++u) {
            ax += __uint_as_float(v[u] << 16);
            ay += __uint_as_float(v[u] & 0xffff0000u);
        }
    }
    for (; idx + 4 <= end; idx += 4) {
        int s0 = bucket[idx + 0], s1 = bucket[idx + 1];
        int s2 = bucket[idx + 2], s3 = bucket[idx + 3];
        unsigned int v0 = p_bf[(size_t)s0 * 64 + lane];
        unsigned int v1 = p_bf[(size_t)s1 * 64 + lane];
        unsigned int v2 = p_bf[(size_t)s2 * 64 + lane];
        unsigned int v3 = p_bf[(size_t)s3 * 64 + lane];
        ax += __uint_as_float(v0 << 16) + __uint_as_float(v1 << 16)
            + __uint_as_float(v2 << 16) + __uint_as_float(v3 << 16);
        ay += __uint_as_float(v0 & 0xffff0000u) + __uint_as_float(v1 & 0xffff0000u)
            + __uint_as_float(v2 & 0xffff0000u) + __uint_as_float(v3 & 0xffff0000u);
    }
    for (; idx < end; ++idx) {
        int s = bucket[idx];
        unsigned int v = p_bf[(size_t)s * 64 + lane];
        ax += __uint_as_float(v << 16);
        ay += __uint_as_float(v & 0xffff0000u);
    }
    float dinv = 1.0f / deg_out[row];
    f32x2 o;
    o[0] = ax * dinv;
    o[1] = ay * dinv;
    f32x2* dp = (f32x2*)dst + (size_t)row * 64 + lane;
    __builtin_nontemporal_store(o, dp);
}

extern "C" void kernel_launch(void* const* d_in, const int* in_sizes, int n_in,
                              void* d_out, int out_size, void* d_ws, size_t ws_size,
                              hipStream_t stream) {
    const float* x_src = (const float*)d_in[0];
    const float* W_src = (const float*)d_in[2];
    const int* edge_src = (const int*)d_in[4];
    const int* edge_dst = (const int*)d_in[5];

    const int N_SRC = in_sizes[0] / D_SRC;
    const int N_DST = in_sizes[1] / D_SRC;
    const int E = in_sizes[4];

    float* out_dst = (float*)d_out;                          // [N_DST, 128]
    float* out_psrc = out_dst + (size_t)N_DST * D_REL;       // [N_SRC, 128]
    float* out_deg = out_psrc + (size_t)N_SRC * D_REL;       // [N_DST]

    int* deg_i = (int*)d_ws;               // N_DST
    int* incl = deg_i + N_DST;             // N_DST
    int* row_start = incl + N_DST;         // N_DST+1
    int* bsums = row_start + N_DST + 1;    // 128
    int* pos_arr = bsums + 128;            // E
    int* bucket = pos_arr + E;             // E
    size_t int_bytes = (size_t)(3 * N_DST + 1 + 128 + 2 * (size_t)E) * sizeof(int);
    size_t wt_off = (int_bytes + 255) & ~(size_t)255;
    bf16x8* Wt = (bf16x8*)((char*)d_ws + wt_off);            // 64 KB
    size_t pbf_off = wt_off + 65536;
    unsigned short* p_bf = (unsigned short*)((char*)d_ws + pbf_off);  // N_SRC*128 bf16

    // 1. W fragments + zero deg_i (no hipMemsetAsync / fillBuffer nodes)
    prep_w_kernel<<<64, 64, 0, stream>>>(W_src, Wt, deg_i, N_DST);
    // 2. fused: count (first blocks, overlaps) + projection GEMM (f32 NT + bf16)
    {
        int nproj = (N_SRC + 31) / 32;
        int ncb = 512;
        proj_count_kernel<<<ncb + nproj, 256, 0, stream>>>(
            x_src, (const f32x4*)Wt, out_psrc, p_bf, N_SRC,
            edge_dst, deg_i, pos_arr, E, ncb);
    }
    // 3. scan + finalize
    int nb = (N_DST + 1023) / 1024;
    scan_blocks<<<nb, 1024, 0, stream>>>(deg_i, incl, bsums, N_DST);
    finalize_kernel<<<nb, 1024, 0, stream>>>(deg_i, incl, bsums, row_start, out_deg, N_DST, E);
    // 4. bucket fill (atomic-free)
    fill_kernel<<<(E + 255) / 256, 256, 0, stream>>>(edge_src, edge_dst, row_start, pos_arr, bucket, E);
    // 5. gather + normalize (bf16 source)
    gather_kernel<<<(N_DST + 3) / 4, 256, 0, stream>>>(
        (const unsigned int*)p_bf, row_start, bucket, out_deg, out_dst, N_DST);
}